// Round 12
// baseline (316.932 us; speedup 1.0000x reference)
//
#include <hip/hip_runtime.h>

// TypedCoords2Volume — single-dispatch fused gather.
// One kernel: block = (b, x, 4-row y-tile). Each block scans its batch's
// 2200 atoms directly (26 KB slab, L2-hot), stages the ~14 candidates whose
// 5x5x5 window intersects the block's (x, y-tile) slab into LDS, scatters
// their exact 5x5 (y,z) footprints into an LDS tile [11][4][120] via LDS
// atomicAdd (~350 __expf items/block), then streams the tile to global with
// non-temporal float4 stores. Every 128B line of the 304MB output is written
// exactly once, fully, by one block. No workspace, no extra dispatches.

#define BOX    120
#define NTYPES 11
#define DHALF  2
#define BOX3   (BOX * BOX * BOX)

#define YT     4               // y-rows per block
#define NYT    (BOX / YT)      // 30
#define SCAP   128             // staged atoms per block (avg ~14)
#define TILEF  (NTYPES * YT * BOX)   // 5280 floats = 21120 B

typedef float v4f __attribute__((ext_vector_type(4)));

// ---------------------------------------------------------------------------
__global__ __launch_bounds__(256)
void fused_kernel(const float* __restrict__ coords,
                  const int*  __restrict__ num_atoms_of_type,
                  const int*  __restrict__ offsets,
                  float* __restrict__ out,
                  int natoms) {
    int bid = blockIdx.x;
    int yt = bid % NYT; bid /= NYT;
    int x  = bid % BOX; bid /= BOX;
    int b  = bid;
    int y0 = yt * YT;
    float xf = (float)x;

    __shared__ __align__(16) float tile[TILEF];   // [type][yl][z]
    __shared__ float4 srt[SCAP];                  // (ay, az, dx^2, type)
    __shared__ int cnt;

    float4* t4 = reinterpret_cast<float4*>(tile);
    for (int i = threadIdx.x; i < TILEF / 4; i += 256)
        t4[i] = make_float4(0.f, 0.f, 0.f, 0.f);
    if (threadIdx.x == 0) cnt = 0;
    __syncthreads();

    const int* off = offsets           + b * NTYPES;
    const int* num = num_atoms_of_type + b * NTYPES;
    const float* cbase = coords + (long long)b * natoms * 3;

    // ---- scan all atoms of this batch; stage candidates ----
    float ylo = (float)(y0 - DHALF);
    float yhi = (float)(y0 + YT - 1 + DHALF);
    for (int j = threadIdx.x; j < natoms; j += 256) {
        float ax = cbase[j * 3 + 0];
        float ay = cbase[j * 3 + 1];
        float az = cbase[j * 3 + 2];
        float abx = floorf(ax);
        float aby = floorf(ay);
        // block-uniform x window + y-tile window (cheap reject first)
        if (fabsf(xf - abx) > (float)DHALF) continue;
        if (aby < ylo || aby > yhi) continue;
        // type + validity (searchsorted over offsets)
        int t = 0;
#pragma unroll
        for (int k = 1; k < NTYPES; ++k)
            if (off[k] <= j) t = k;
        if (!(j >= off[t] && j < off[t] + num[t])) continue;

        int slot = atomicAdd(&cnt, 1);
        if (slot < SCAP) {
            float dx = xf - ax;
            srt[slot] = make_float4(ay, az, dx * dx, __int_as_float(t));
        }
    }
    __syncthreads();
    int n = min(cnt, SCAP);

    // ---- scatter: one item per (atom, 5y x 5z window voxel) ----
    for (int w = threadIdx.x; w < n * 25; w += 256) {
        int j   = w / 25;
        int rem = w - j * 25;
        int iy  = rem / 5;
        int iz  = rem - iy * 5;
        float4 a = srt[j];
        float ay = a.x, az = a.y, dx2 = a.z;
        int t   = __float_as_int(a.w);
        int aby = (int)floorf(ay);
        int abz = (int)floorf(az);
        int cy  = aby + iy - DHALF;
        int cz  = abz + iz - DHALF;
        if (cy < y0 || cy >= y0 + YT || (unsigned)cz >= (unsigned)BOX) continue;
        float dy = (float)cy - ay;
        float dz = (float)cz - az;
        float r2 = fmaf(dy, dy, fmaf(dz, dz, dx2));
        float v  = __expf(-r2);
        atomicAdd(&tile[(t * YT + (cy - y0)) * BOX + cz], v);
    }
    __syncthreads();

    // ---- stream tile to global: 11 contiguous 1920B chunks, aligned,
    //      non-temporal (output is write-once, never re-read) ----
    long long obase = (long long)b * NTYPES * BOX3
                    + (long long)x * (BOX * BOX) + (long long)y0 * BOX;
    const v4f* t4v = reinterpret_cast<const v4f*>(tile);
    const int C4 = YT * BOX / 4;                 // 120 float4 per type chunk
    for (int i = threadIdx.x; i < NTYPES * C4; i += 256) {
        int k = i / C4;             // type
        int r = i - k * C4;         // float4 index within chunk
        v4f v = t4v[k * C4 + r];
        __builtin_nontemporal_store(
            v, reinterpret_cast<v4f*>(&out[obase + (long long)k * BOX3 + r * 4]));
    }
}

// ---------------------------------------------------------------------------
extern "C" void kernel_launch(void* const* d_in, const int* in_sizes, int n_in,
                              void* d_out, int out_size, void* d_ws, size_t ws_size,
                              hipStream_t stream) {
    const float* coords = (const float*)d_in[0];
    const int*   num    = (const int*)d_in[1];
    const int*   off    = (const int*)d_in[2];
    float*       out    = (float*)d_out;

    int batch  = in_sizes[1] / NTYPES;        // [B, NTYPES]
    int natoms = in_sizes[0] / (3 * batch);   // [B, NATOMS*3]

    fused_kernel<<<batch * BOX * NYT, 256, 0, stream>>>(
        coords, num, off, out, natoms);
}